// Round 3
// baseline (201.419 us; speedup 1.0000x reference)
//
#include <hip/hip_runtime.h>

typedef unsigned short u16;
typedef __bf16 b16x8_t __attribute__((ext_vector_type(8)));
typedef unsigned short u16x8 __attribute__((ext_vector_type(8)));
typedef float f32x4 __attribute__((ext_vector_type(4)));

__device__ __forceinline__ u16 f2bf(float f) {
  union { float f; unsigned u; } x; x.f = f;
  unsigned r = x.u + 0x7fffu + ((x.u >> 16) & 1u);
  return (u16)(r >> 16);
}

__device__ __forceinline__ f32x4 mfma16(u16x8 a, u16x8 b, f32x4 c) {
  return __builtin_amdgcn_mfma_f32_16x16x32_bf16(
      __builtin_bit_cast(b16x8_t, a), __builtin_bit_cast(b16x8_t, b), c, 0, 0, 0);
}

__device__ __forceinline__ void gld_lds16(const void* g, void* l) {
  __builtin_amdgcn_global_load_lds(
      (const __attribute__((address_space(1))) void*)g,
      (__attribute__((address_space(3))) void*)l, 16, 0, 0);
}

__device__ __forceinline__ void store_out(float* p, float v) { *p = v; }
__device__ __forceinline__ void store_out(u16* p, float v) { *p = f2bf(v); }

// ---------------- elementwise f32 -> bf16 ----------------
__global__ void convert_bf16(const float* __restrict__ src, u16* __restrict__ dst, int n4) {
  int i = blockIdx.x * blockDim.x + threadIdx.x;
  if (i < n4) {
    float4 f = ((const float4*)src)[i];
    u16 a0 = f2bf(f.x), a1 = f2bf(f.y), a2 = f2bf(f.z), a3 = f2bf(f.w);
    unsigned lo = (unsigned)a0 | ((unsigned)a1 << 16);
    unsigned hi = (unsigned)a2 | ((unsigned)a3 << 16);
    ((uint2*)dst)[i] = make_uint2(lo, hi);
  }
}

// ---------------- f32 [R][C] -> bf16 transposed [C][R] ----------------
__global__ void transpose_f32_bf16(const float* __restrict__ src, u16* __restrict__ dst,
                                   int R, int Cn) {
  __shared__ float t[32][33];
  int c0 = blockIdx.x * 32, r0 = blockIdx.y * 32;
  int tx = threadIdx.x, ty = threadIdx.y;  // (32,8)
  for (int j = 0; j < 32; j += 8)
    t[ty + j][tx] = src[(size_t)(r0 + ty + j) * Cn + c0 + tx];
  __syncthreads();
  for (int j = 0; j < 32; j += 8)
    dst[(size_t)(c0 + ty + j) * R + r0 + tx] = f2bf(t[tx][ty + j]);
}

// ---------------- V pre-transpose: qkv V-part -> Vt[(b*16+h)*64+k][n] ----------------
__global__ void transpose_v(const u16* __restrict__ QKV, u16* __restrict__ Vt) {
  __shared__ u16 t[64][72];
  const int tid = threadIdx.x;
  const int ntb = blockIdx.x, h = blockIdx.y, bb = blockIdx.z;
  const size_t rowb = (size_t)bb * 1024 + ntb * 64;
  const int colV = h * 192 + 128;
  for (int it = 0; it < 2; ++it) {
    int i2 = tid + it * 256;
    int n = i2 >> 3, kk = (i2 & 7) * 8;
    u16x8 v = *(const u16x8*)(QKV + (rowb + n) * 3072 + colV + kk);
#pragma unroll
    for (int u = 0; u < 8; ++u) t[kk + u][n] = v[u];
  }
  __syncthreads();
  const size_t vb = ((size_t)bb * 16 + h) * 64;
  for (int it = 0; it < 2; ++it) {
    int i2 = tid + it * 256;
    int k = i2 >> 3, ns = (i2 & 7) * 8;
    *(u16x8*)(Vt + (vb + k) * 1024 + ntb * 64 + ns) = *(const u16x8*)(&t[k][ns]);
  }
}

// ---------------- bf16 GEMM v2: C[M][N] = A[M][K] * Bt[N][K]^T ----------------
// BM=128, BN=256, BK=32, 4 LDS buffers, 512 thr (8 waves 2x4), per-wave 64x64.
// Depth-3 prefetch with counted vmcnt (6 in-flight), raw s_barrier (1/iter),
// T2 LDS swizzle (c ^= ((row>>1)&3)<<3) via inverse-swizzled global source,
// T5 setprio around MFMA cluster, T1 bijective XCD swizzle (nwg%8==0).
template <typename OutT, bool SCALEQ>
__global__ __launch_bounds__(512, 2) void gemm_bt2(const u16* __restrict__ A,
                                                   const u16* __restrict__ Bt,
                                                   OutT* __restrict__ C,
                                                   int M, int N, int K) {
  __shared__ __align__(16) u16 sA[4][128 * 32];
  __shared__ __align__(16) u16 sB[4][256 * 32];
  const int tid = threadIdx.x, lane = tid & 63, wid = tid >> 6;
  const int hi = lane >> 4, ln = lane & 15;

  // XCD-aware block swizzle (bijective since nwg % 8 == 0)
  const int nwg = gridDim.x * gridDim.y;
  int wg = blockIdx.y * gridDim.x + blockIdx.x;
  wg = (wg & 7) * (nwg >> 3) + (wg >> 3);
  const int m0 = (wg / gridDim.x) * 128;
  const int n0 = (wg % gridDim.x) * 256;

  // staging geometry: thread -> (row = tid/4, col16 = (tid%4)*8), source col
  // pre-swizzled so linear LDS dest holds swizzled layout
  const int sr = tid >> 2;
  const int scsw = ((tid & 3) * 8) ^ ((((tid >> 2) >> 1) & 3) << 3);
  const u16* srcA = A + (size_t)(m0 + sr) * K + scsw;
  const u16* srcB0 = Bt + (size_t)(n0 + sr) * K + scsw;
  const u16* srcB1 = srcB0 + (size_t)128 * K;

  auto stage = [&](int t) {
    const int buf = t & 3;
    const int k0 = t * 32;
    gld_lds16(srcA + k0, &sA[buf][tid * 8]);
    gld_lds16(srcB0 + k0, &sB[buf][tid * 8]);
    gld_lds16(srcB1 + k0, &sB[buf][4096 + tid * 8]);
  };

  // per-wave fragment read offsets (u16 units, swizzled)
  const int wm = (wid >> 2) * 64, wn = (wid & 3) * 64;
  int offA[4], offB[4];
#pragma unroll
  for (int i = 0; i < 4; ++i) {
    int row = wm + i * 16 + ln;
    offA[i] = row * 32 + ((hi * 8) ^ (((row >> 1) & 3) << 3));
  }
#pragma unroll
  for (int j = 0; j < 4; ++j) {
    int row = wn + j * 16 + ln;
    offB[j] = row * 32 + ((hi * 8) ^ (((row >> 1) & 3) << 3));
  }

  f32x4 acc[4][4] = {};
  const int NT = K >> 5;
  stage(0); stage(1); stage(2);

  for (int t = 0; t < NT; ++t) {
    const int rem = NT - 1 - t;
    if (rem >= 2)      asm volatile("s_waitcnt vmcnt(6)" ::: "memory");
    else if (rem == 1) asm volatile("s_waitcnt vmcnt(3)" ::: "memory");
    else               asm volatile("s_waitcnt vmcnt(0)" ::: "memory");
    __builtin_amdgcn_s_barrier();
    __builtin_amdgcn_sched_barrier(0);
    if (t + 3 < NT) stage(t + 3);
    const int buf = t & 3;
    u16x8 af[4], bf[4];
#pragma unroll
    for (int i = 0; i < 4; ++i) af[i] = *(const u16x8*)(&sA[buf][offA[i]]);
#pragma unroll
    for (int j = 0; j < 4; ++j) bf[j] = *(const u16x8*)(&sB[buf][offB[j]]);
    __builtin_amdgcn_s_setprio(1);
#pragma unroll
    for (int i = 0; i < 4; ++i)
#pragma unroll
      for (int j = 0; j < 4; ++j)
        acc[i][j] = mfma16(af[i], bf[j], acc[i][j]);
    __builtin_amdgcn_s_setprio(0);
  }

  // epilogue: C/D layout col = lane&15, row = (lane>>4)*4 + reg
#pragma unroll
  for (int i = 0; i < 4; ++i) {
    int row = m0 + wm + i * 16 + hi * 4;
#pragma unroll
    for (int j = 0; j < 4; ++j) {
      int col = n0 + wn + j * 16 + ln;
      float sc = 1.f;
      if (SCALEQ) { if ((col % 192) < 64) sc = 0.125f; }
#pragma unroll
      for (int r = 0; r < 4; ++r)
        store_out(&C[(size_t)(row + r) * N + col], acc[i][j][r] * sc);
    }
  }
}

// ---------------- causal flash attention v2 ----------------
// grid (z=4, h=16, b=8), 512 thr (8 waves x 16 q-rows). Block does q-tiles z and 7-z
// (equal 18 KV-iterations each). K/V double-buffered via global_load_lds with
// XOR-swizzled source; V pre-transposed globally. Q scaled by 0.125 upstream.
__global__ __launch_bounds__(512, 4) void attn_fwd2(const u16* __restrict__ QKV,
                                                    const u16* __restrict__ Vt,
                                                    u16* __restrict__ O) {
  __shared__ __align__(16) u16 sK[2][4096];
  __shared__ __align__(16) u16 sVt[2][4096];
  __shared__ __align__(16) u16 sP[8][16 * 72];
  const int tid = threadIdx.x, lane = tid & 63, wid = tid >> 6;
  const int z = blockIdx.x, h = blockIdx.y, bb = blockIdx.z;
  const size_t rowbase = (size_t)bb * 1024;
  const size_t vbase = ((size_t)bb * 16 + h) * 64;
  const int colQ = h * 192, colK = colQ + 64;
  const int hi = lane >> 4, ln = lane & 15;
  const int slr = lane >> 3;
  const int sle = ((lane & 7) ^ slr) * 8;
  u16* sPw = sP[wid];

  auto stageKV = [&](int buf, int nt) {
    const int n0g = nt * 64;
    gld_lds16(QKV + (rowbase + n0g + 8 * wid + slr) * 3072 + colK + sle,
              &sK[buf][wid * 512]);
    gld_lds16(Vt + (vbase + 8 * wid + slr) * 1024 + n0g + sle,
              &sVt[buf][wid * 512]);
  };

  for (int half = 0; half < 2; ++half) {
    const int mt = half ? (7 - z) : z;
    const int qrow0 = mt * 128 + wid * 16;
    const int ntiles = 2 * mt + 2;

    u16x8 qf[2];
#pragma unroll
    for (int kb = 0; kb < 2; ++kb)
      qf[kb] = *(const u16x8*)(QKV + (rowbase + qrow0 + ln) * 3072 + colQ + kb * 32 + hi * 8);

    f32x4 o[4] = {};
    float mrow[4], lrow[4];
#pragma unroll
    for (int r = 0; r < 4; ++r) { mrow[r] = -1e30f; lrow[r] = 0.f; }

    stageKV(0, 0);
    for (int nt = 0; nt < ntiles; ++nt) {
      __syncthreads();
      if (nt + 1 < ntiles) stageKV((nt + 1) & 1, nt + 1);
      const int buf = nt & 1;
      const int n0g = nt * 64;
      if (n0g <= qrow0 + 15) {
        f32x4 s[4] = {};
#pragma unroll
        for (int kb = 0; kb < 2; ++kb)
#pragma unroll
          for (int j = 0; j < 4; ++j) {
            int row = j * 16 + ln;
            int cb = (kb * 64 + hi * 16) ^ ((row & 7) << 4);
            u16x8 kfr = *(const u16x8*)(&sK[buf][(row * 128 + cb) >> 1]);
            s[j] = mfma16(qf[kb], kfr, s[j]);
          }
        if (n0g + 63 > qrow0) {
#pragma unroll
          for (int j = 0; j < 4; ++j) {
            int col = n0g + j * 16 + ln;
#pragma unroll
            for (int r = 0; r < 4; ++r)
              if (col > qrow0 + hi * 4 + r) s[j][r] = -3e38f;
          }
        }
#pragma unroll
        for (int r = 0; r < 4; ++r) {
          float tm = fmaxf(fmaxf(s[0][r], s[1][r]), fmaxf(s[2][r], s[3][r]));
#pragma unroll
          for (int d = 1; d < 16; d <<= 1) tm = fmaxf(tm, __shfl_xor(tm, d, 64));
          float mnew = fmaxf(mrow[r], tm);
          float corr = __expf(mrow[r] - mnew);
          mrow[r] = mnew;
          float rs = 0.f;
#pragma unroll
          for (int j = 0; j < 4; ++j) {
            float p = __expf(s[j][r] - mnew);
            s[j][r] = p;
            rs += p;
          }
#pragma unroll
          for (int d = 1; d < 16; d <<= 1) rs += __shfl_xor(rs, d, 64);
          lrow[r] = lrow[r] * corr + rs;
#pragma unroll
          for (int dt = 0; dt < 4; ++dt) o[dt][r] *= corr;
        }
#pragma unroll
        for (int j = 0; j < 4; ++j)
#pragma unroll
          for (int r = 0; r < 4; ++r)
            sPw[(hi * 4 + r) * 72 + j * 16 + ln] = f2bf(s[j][r]);
        u16x8 pf[2];
#pragma unroll
        for (int kb2 = 0; kb2 < 2; ++kb2)
          pf[kb2] = *(const u16x8*)(&sPw[ln * 72 + kb2 * 32 + hi * 8]);
#pragma unroll
        for (int dt = 0; dt < 4; ++dt)
#pragma unroll
          for (int kb2 = 0; kb2 < 2; ++kb2) {
            int row = dt * 16 + ln;
            int cb = (kb2 * 64 + hi * 16) ^ ((row & 7) << 4);
            u16x8 vfr = *(const u16x8*)(&sVt[buf][(row * 128 + cb) >> 1]);
            o[dt] = mfma16(pf[kb2], vfr, o[dt]);
          }
      }
    }
#pragma unroll
    for (int r = 0; r < 4; ++r) {
      float inv = 1.f / lrow[r];
#pragma unroll
      for (int dt = 0; dt < 4; ++dt)
        O[(rowbase + qrow0 + hi * 4 + r) * 1024 + h * 64 + dt * 16 + ln] =
            f2bf(o[dt][r] * inv);
    }
  }
}

extern "C" void kernel_launch(void* const* d_in, const int* in_sizes, int n_in,
                              void* d_out, int out_size, void* d_ws, size_t ws_size,
                              hipStream_t stream) {
  const float* x = (const float*)d_in[0];
  const float* Pi = (const float*)d_in[1];
  const float* Po = (const float*)d_in[2];
  float* y = (float*)d_out;
  char* ws = (char*)d_ws;

  u16* qkv  = (u16*)(ws);                     // 50331648
  u16* xbf  = (u16*)(ws + 50331648);          // 16777216
  u16* vt   = (u16*)(ws + 50331648);          // reuses xbf slot
  u16* piT  = (u16*)(ws + 67108864);          // 6291456
  u16* poT  = (u16*)(ws + 73400320);          // 2097152
  u16* obuf = (u16*)(ws + 75497472);          // 16777216

  convert_bf16<<<8192, 256, 0, stream>>>(x, xbf, 8388608 / 4);
  dim3 tb(32, 8);
  transpose_f32_bf16<<<dim3(96, 32), tb, 0, stream>>>(Pi, piT, 1024, 3072);
  transpose_f32_bf16<<<dim3(32, 32), tb, 0, stream>>>(Po, poT, 1024, 1024);

  gemm_bt2<u16, true><<<dim3(12, 64), 512, 0, stream>>>(xbf, piT, qkv, 8192, 3072, 1024);
  transpose_v<<<dim3(16, 16, 8), 256, 0, stream>>>(qkv, vt);
  attn_fwd2<<<dim3(4, 16, 8), 512, 0, stream>>>(qkv, vt, obuf);
  gemm_bt2<float, false><<<dim3(4, 64), 512, 0, stream>>>(obuf, poT, y, 8192, 1024, 1024);
}

// Round 4
// 188.335 us; speedup vs baseline: 1.0695x; 1.0695x over previous
//
#include <hip/hip_runtime.h>

typedef unsigned short u16;
typedef __bf16 b16x8_t __attribute__((ext_vector_type(8)));
typedef unsigned short u16x8 __attribute__((ext_vector_type(8)));
typedef float f32x4 __attribute__((ext_vector_type(4)));

__device__ __forceinline__ u16 f2bf(float f) {
  union { float f; unsigned u; } x; x.f = f;
  unsigned r = x.u + 0x7fffu + ((x.u >> 16) & 1u);
  return (u16)(r >> 16);
}

__device__ __forceinline__ f32x4 mfma16(u16x8 a, u16x8 b, f32x4 c) {
  return __builtin_amdgcn_mfma_f32_16x16x32_bf16(
      __builtin_bit_cast(b16x8_t, a), __builtin_bit_cast(b16x8_t, b), c, 0, 0, 0);
}

__device__ __forceinline__ void gld_lds16(const void* g, void* l) {
  __builtin_amdgcn_global_load_lds(
      (const __attribute__((address_space(1))) void*)g,
      (__attribute__((address_space(3))) void*)l, 16, 0, 0);
}

__device__ __forceinline__ void store_out(float* p, float v) { *p = v; }
__device__ __forceinline__ void store_out(u16* p, float v) { *p = f2bf(v); }

// ---------------- elementwise f32 -> bf16 ----------------
__global__ void convert_bf16(const float* __restrict__ src, u16* __restrict__ dst, int n4) {
  int i = blockIdx.x * blockDim.x + threadIdx.x;
  if (i < n4) {
    float4 f = ((const float4*)src)[i];
    u16 a0 = f2bf(f.x), a1 = f2bf(f.y), a2 = f2bf(f.z), a3 = f2bf(f.w);
    unsigned lo = (unsigned)a0 | ((unsigned)a1 << 16);
    unsigned hi = (unsigned)a2 | ((unsigned)a3 << 16);
    ((uint2*)dst)[i] = make_uint2(lo, hi);
  }
}

// ---------------- f32 [R][C] -> bf16 transposed [C][R] ----------------
__global__ void transpose_f32_bf16(const float* __restrict__ src, u16* __restrict__ dst,
                                   int R, int Cn) {
  __shared__ float t[32][33];
  int c0 = blockIdx.x * 32, r0 = blockIdx.y * 32;
  int tx = threadIdx.x, ty = threadIdx.y;  // (32,8)
  for (int j = 0; j < 32; j += 8)
    t[ty + j][tx] = src[(size_t)(r0 + ty + j) * Cn + c0 + tx];
  __syncthreads();
  for (int j = 0; j < 32; j += 8)
    dst[(size_t)(c0 + ty + j) * R + r0 + tx] = f2bf(t[tx][ty + j]);
}

// ---------------- V pre-transpose: qkv V-part -> Vt[(b*16+h)*64+k][n] ----------------
__global__ void transpose_v(const u16* __restrict__ QKV, u16* __restrict__ Vt) {
  __shared__ u16 t[64][72];
  const int tid = threadIdx.x;
  const int ntb = blockIdx.x, h = blockIdx.y, bb = blockIdx.z;
  const size_t rowb = (size_t)bb * 1024 + ntb * 64;
  const int colV = h * 192 + 128;
  for (int it = 0; it < 2; ++it) {
    int i2 = tid + it * 256;
    int n = i2 >> 3, kk = (i2 & 7) * 8;
    u16x8 v = *(const u16x8*)(QKV + (rowb + n) * 3072 + colV + kk);
#pragma unroll
    for (int u = 0; u < 8; ++u) t[kk + u][n] = v[u];
  }
  __syncthreads();
  const size_t vb = ((size_t)bb * 16 + h) * 64;
  for (int it = 0; it < 2; ++it) {
    int i2 = tid + it * 256;
    int k = i2 >> 3, ns = (i2 & 7) * 8;
    *(u16x8*)(Vt + (vb + k) * 1024 + ntb * 64 + ns) = *(const u16x8*)(&t[k][ns]);
  }
}

// ---------------- bf16 GEMM, m201-style 8-phase: C = A * Bt^T ----------------
// BM=BN=256, BK=64, 512 thr (8 waves 2Mx4N), per-wave 128x64 (acc[8][4]).
// 2 LDS buffers x 2 halves per operand (128 KiB). 8 phases / 2 K-tiles;
// counted vmcnt(6) before the trailing barrier of phases 4 and 8.
// Zero-conflict swizzle: 16B-chunk XOR (row&7) via pre-swizzled global source.
template <typename OutT, bool SCALEQ>
__global__ __launch_bounds__(512, 2) void gemm8p(const u16* __restrict__ A,
                                                 const u16* __restrict__ Bt,
                                                 OutT* __restrict__ C,
                                                 int M, int N, int K) {
  __shared__ __align__(16) u16 sA[2][2][8192];   // [buf][half][128*64]
  __shared__ __align__(16) u16 sB[2][2][8192];
  const int tid = threadIdx.x, lane = tid & 63, wid = tid >> 6;
  const int hi = lane >> 4, ln = lane & 15;
  const int wr = wid >> 2, wc = wid & 3;

  // XCD-aware bijective swizzle (nwg % 8 == 0 for both call sites)
  const int gdx = gridDim.x;
  const int nwg = gdx * gridDim.y;
  int wg = blockIdx.y * gdx + blockIdx.x;
  wg = (wg & 7) * (nwg >> 3) + (wg >> 3);
  const int m0 = (wg / gdx) * 256;
  const int n0 = (wg % gdx) * 256;

  // staging: thread t covers row (t>>3), 16B-chunk (t&7); src chunk pre-swizzled
  const int srow = tid >> 3;
  const int sc = ((tid & 7) ^ (srow & 7)) * 8;
  const u16* srcA = A + (size_t)(m0 + srow) * K + sc;
  const u16* srcB = Bt + (size_t)(n0 + srow) * K + sc;

  auto stageA = [&](int kt, int h) {
    const u16* s = srcA + ((size_t)h * 128) * K + kt * 64;
    u16* d = &sA[kt & 1][h][tid * 8];
    gld_lds16(s, d);
    gld_lds16(s + (size_t)64 * K, d + 4096);
  };
  auto stageB = [&](int kt, int h) {
    const u16* s = srcB + ((size_t)h * 128) * K + kt * 64;
    u16* d = &sB[kt & 1][h][tid * 8];
    gld_lds16(s, d);
    gld_lds16(s + (size_t)64 * K, d + 4096);
  };

  // fragment read offsets (u16 units) within a half-buffer
  int swz[2];
#pragma unroll
  for (int kk = 0; kk < 2; ++kk) swz[kk] = (kk * 32 + hi * 8) ^ ((ln & 7) << 3);
  const int rowA = ln * 64;
  const int bq = (wc & 1) * 4096;  // B row-offset within its half

  auto ldA = [&](u16x8* dst, int buf, int mq) {  // 4 frags x 2 kk
#pragma unroll
    for (int i = 0; i < 4; ++i)
#pragma unroll
      for (int kk = 0; kk < 2; ++kk)
        dst[i * 2 + kk] = *(const u16x8*)(&sA[buf][wr][(mq * 4 + i) * 1024 + rowA + swz[kk]]);
  };
  auto ldB = [&](u16x8* dst, int buf, int nq) {  // 2 frags x 2 kk
#pragma unroll
    for (int j = 0; j < 2; ++j)
#pragma unroll
      for (int kk = 0; kk < 2; ++kk)
        dst[j * 2 + kk] = *(const u16x8*)(&sB[buf][wc >> 1][bq + (nq * 2 + j) * 1024 + rowA + swz[kk]]);
  };

  f32x4 acc[8][4] = {};

  auto PRE = [&] {
    __builtin_amdgcn_s_barrier();
    asm volatile("s_waitcnt lgkmcnt(0)" ::: "memory");
    __builtin_amdgcn_sched_barrier(0);
    __builtin_amdgcn_s_setprio(1);
  };
  auto END = [&] {
    __builtin_amdgcn_s_setprio(0);
    __builtin_amdgcn_sched_barrier(0);
    __builtin_amdgcn_s_barrier();
  };

  u16x8 a0[8], a1[8], b0[4], b1[4];
  auto MMA = [&](const u16x8* a, const u16x8* b, int mq, int nq) {
#pragma unroll
    for (int i = 0; i < 4; ++i)
#pragma unroll
      for (int j = 0; j < 2; ++j)
#pragma unroll
        for (int kk = 0; kk < 2; ++kk)
          acc[mq * 4 + i][nq * 2 + j] =
              mfma16(a[i * 2 + kk], b[j * 2 + kk], acc[mq * 4 + i][nq * 2 + j]);
  };

  const int NT = K >> 6;  // 16 for K=1024
  // prologue: tile0 all 4 halves, tile1 B0,B1,A0 (A1 staged at P1 of iter 0)
  stageB(0, 0); stageB(0, 1); stageA(0, 0); stageA(0, 1);
  stageB(1, 0); stageB(1, 1); stageA(1, 0);
  asm volatile("s_waitcnt vmcnt(6)" ::: "memory");
  __builtin_amdgcn_s_barrier();

  for (int it = 0; it < NT / 2; ++it) {
    const int kt0 = 2 * it, kt1 = kt0 + 1, kt2 = kt0 + 2, kt3 = kt0 + 3;
    const int bf0 = kt0 & 1, bf1 = kt1 & 1;
    const bool s2 = kt2 < NT, s3 = kt3 < NT;
    // ---- K-tile kt0 ----
    // P1
    ldA(a0, bf0, 0); ldB(b0, bf0, 0);
    stageA(kt1, 1);
    PRE(); MMA(a0, b0, 0, 0); END();
    // P2
    ldB(b1, bf0, 1);
    PRE(); MMA(a0, b1, 0, 1); END();
    // P3
    ldA(a1, bf0, 1);
    if (s2) { stageB(kt2, 0); stageB(kt2, 1); }
    PRE(); MMA(a1, b0, 1, 0); END();
    // P4 (checkpoint)
    if (s2) stageA(kt2, 0);
    PRE(); MMA(a1, b1, 1, 1);
    __builtin_amdgcn_s_setprio(0);
    __builtin_amdgcn_sched_barrier(0);
    if (s2) asm volatile("s_waitcnt vmcnt(6)" ::: "memory");
    else    asm volatile("s_waitcnt vmcnt(0)" ::: "memory");
    __builtin_amdgcn_s_barrier();
    // ---- K-tile kt1 ----
    // P5
    ldA(a0, bf1, 0); ldB(b0, bf1, 0);
    if (s2) stageA(kt2, 1);
    PRE(); MMA(a0, b0, 0, 0); END();
    // P6
    ldB(b1, bf1, 1);
    PRE(); MMA(a0, b1, 0, 1); END();
    // P7
    ldA(a1, bf1, 1);
    if (s3) { stageB(kt3, 0); stageB(kt3, 1); }
    PRE(); MMA(a1, b0, 1, 0); END();
    // P8 (checkpoint)
    if (s3) stageA(kt3, 0);
    PRE(); MMA(a1, b1, 1, 1);
    __builtin_amdgcn_s_setprio(0);
    __builtin_amdgcn_sched_barrier(0);
    if (s3) asm volatile("s_waitcnt vmcnt(6)" ::: "memory");
    else    asm volatile("s_waitcnt vmcnt(0)" ::: "memory");
    __builtin_amdgcn_s_barrier();
  }

  // epilogue: C/D layout col = lane&15, row = (lane>>4)*4 + reg
#pragma unroll
  for (int i = 0; i < 8; ++i) {
    int row = m0 + wr * 128 + i * 16 + hi * 4;
#pragma unroll
    for (int j = 0; j < 4; ++j) {
      int col = n0 + wc * 64 + j * 16 + ln;
      float sc2 = 1.f;
      if (SCALEQ) { if ((col % 192) < 64) sc2 = 0.125f; }
#pragma unroll
      for (int r = 0; r < 4; ++r)
        store_out(&C[(size_t)(row + r) * N + col], acc[i][j][r] * sc2);
    }
  }
}

// ---------------- causal flash attention v2 ----------------
__global__ __launch_bounds__(512, 4) void attn_fwd2(const u16* __restrict__ QKV,
                                                    const u16* __restrict__ Vt,
                                                    u16* __restrict__ O) {
  __shared__ __align__(16) u16 sK[2][4096];
  __shared__ __align__(16) u16 sVt[2][4096];
  __shared__ __align__(16) u16 sP[8][16 * 72];
  const int tid = threadIdx.x, lane = tid & 63, wid = tid >> 6;
  const int z = blockIdx.x, h = blockIdx.y, bb = blockIdx.z;
  const size_t rowbase = (size_t)bb * 1024;
  const size_t vbase = ((size_t)bb * 16 + h) * 64;
  const int colQ = h * 192, colK = colQ + 64;
  const int hi = lane >> 4, ln = lane & 15;
  const int slr = lane >> 3;
  const int sle = ((lane & 7) ^ slr) * 8;
  u16* sPw = sP[wid];

  auto stageKV = [&](int buf, int nt) {
    const int n0g = nt * 64;
    gld_lds16(QKV + (rowbase + n0g + 8 * wid + slr) * 3072 + colK + sle,
              &sK[buf][wid * 512]);
    gld_lds16(Vt + (vbase + 8 * wid + slr) * 1024 + n0g + sle,
              &sVt[buf][wid * 512]);
  };

  for (int half = 0; half < 2; ++half) {
    const int mt = half ? (7 - z) : z;
    const int qrow0 = mt * 128 + wid * 16;
    const int ntiles = 2 * mt + 2;

    u16x8 qf[2];
#pragma unroll
    for (int kb = 0; kb < 2; ++kb)
      qf[kb] = *(const u16x8*)(QKV + (rowbase + qrow0 + ln) * 3072 + colQ + kb * 32 + hi * 8);

    f32x4 o[4] = {};
    float mrow[4], lrow[4];
#pragma unroll
    for (int r = 0; r < 4; ++r) { mrow[r] = -1e30f; lrow[r] = 0.f; }

    stageKV(0, 0);
    for (int nt = 0; nt < ntiles; ++nt) {
      __syncthreads();
      if (nt + 1 < ntiles) stageKV((nt + 1) & 1, nt + 1);
      const int buf = nt & 1;
      const int n0g = nt * 64;
      if (n0g <= qrow0 + 15) {
        f32x4 s[4] = {};
#pragma unroll
        for (int kb = 0; kb < 2; ++kb)
#pragma unroll
          for (int j = 0; j < 4; ++j) {
            int row = j * 16 + ln;
            int cb = (kb * 64 + hi * 16) ^ ((row & 7) << 4);
            u16x8 kfr = *(const u16x8*)(&sK[buf][(row * 128 + cb) >> 1]);
            s[j] = mfma16(qf[kb], kfr, s[j]);
          }
        if (n0g + 63 > qrow0) {
#pragma unroll
          for (int j = 0; j < 4; ++j) {
            int col = n0g + j * 16 + ln;
#pragma unroll
            for (int r = 0; r < 4; ++r)
              if (col > qrow0 + hi * 4 + r) s[j][r] = -3e38f;
          }
        }
#pragma unroll
        for (int r = 0; r < 4; ++r) {
          float tm = fmaxf(fmaxf(s[0][r], s[1][r]), fmaxf(s[2][r], s[3][r]));
#pragma unroll
          for (int d = 1; d < 16; d <<= 1) tm = fmaxf(tm, __shfl_xor(tm, d, 64));
          float mnew = fmaxf(mrow[r], tm);
          float corr = __expf(mrow[r] - mnew);
          mrow[r] = mnew;
          float rs = 0.f;
#pragma unroll
          for (int j = 0; j < 4; ++j) {
            float p = __expf(s[j][r] - mnew);
            s[j][r] = p;
            rs += p;
          }
#pragma unroll
          for (int d = 1; d < 16; d <<= 1) rs += __shfl_xor(rs, d, 64);
          lrow[r] = lrow[r] * corr + rs;
#pragma unroll
          for (int dt = 0; dt < 4; ++dt) o[dt][r] *= corr;
        }
#pragma unroll
        for (int j = 0; j < 4; ++j)
#pragma unroll
          for (int r = 0; r < 4; ++r)
            sPw[(hi * 4 + r) * 72 + j * 16 + ln] = f2bf(s[j][r]);
        u16x8 pf[2];
#pragma unroll
        for (int kb2 = 0; kb2 < 2; ++kb2)
          pf[kb2] = *(const u16x8*)(&sPw[ln * 72 + kb2 * 32 + hi * 8]);
#pragma unroll
        for (int dt = 0; dt < 4; ++dt)
#pragma unroll
          for (int kb2 = 0; kb2 < 2; ++kb2) {
            int row = dt * 16 + ln;
            int cb = (kb2 * 64 + hi * 16) ^ ((row & 7) << 4);
            u16x8 vfr = *(const u16x8*)(&sVt[buf][(row * 128 + cb) >> 1]);
            o[dt] = mfma16(pf[kb2], vfr, o[dt]);
          }
      }
    }
#pragma unroll
    for (int r = 0; r < 4; ++r) {
      float inv = 1.f / lrow[r];
#pragma unroll
      for (int dt = 0; dt < 4; ++dt)
        O[(rowbase + qrow0 + hi * 4 + r) * 1024 + h * 64 + dt * 16 + ln] =
            f2bf(o[dt][r] * inv);
    }
  }
}

extern "C" void kernel_launch(void* const* d_in, const int* in_sizes, int n_in,
                              void* d_out, int out_size, void* d_ws, size_t ws_size,
                              hipStream_t stream) {
  const float* x = (const float*)d_in[0];
  const float* Pi = (const float*)d_in[1];
  const float* Po = (const float*)d_in[2];
  float* y = (float*)d_out;
  char* ws = (char*)d_ws;

  u16* qkv  = (u16*)(ws);                     // 50331648
  u16* xbf  = (u16*)(ws + 50331648);          // 16777216
  u16* vt   = (u16*)(ws + 50331648);          // reuses xbf slot
  u16* piT  = (u16*)(ws + 67108864);          // 6291456
  u16* poT  = (u16*)(ws + 73400320);          // 2097152
  u16* obuf = (u16*)(ws + 75497472);          // 16777216

  convert_bf16<<<8192, 256, 0, stream>>>(x, xbf, 8388608 / 4);
  dim3 tb(32, 8);
  transpose_f32_bf16<<<dim3(96, 32), tb, 0, stream>>>(Pi, piT, 1024, 3072);
  transpose_f32_bf16<<<dim3(32, 32), tb, 0, stream>>>(Po, poT, 1024, 1024);

  gemm8p<u16, true><<<dim3(12, 32), 512, 0, stream>>>(xbf, piT, qkv, 8192, 3072, 1024);
  transpose_v<<<dim3(16, 16, 8), 256, 0, stream>>>(qkv, vt);
  attn_fwd2<<<dim3(4, 16, 8), 512, 0, stream>>>(qkv, vt, obuf);
  gemm8p<float, false><<<dim3(4, 32), 512, 0, stream>>>(obuf, poT, y, 8192, 1024, 1024);
}

// Round 5
// 180.419 us; speedup vs baseline: 1.1164x; 1.0439x over previous
//
#include <hip/hip_runtime.h>

typedef unsigned short u16;
typedef __bf16 b16x8_t __attribute__((ext_vector_type(8)));
typedef unsigned short u16x8 __attribute__((ext_vector_type(8)));
typedef float f32x4 __attribute__((ext_vector_type(4)));

__device__ __forceinline__ u16 f2bf(float f) {
  union { float f; unsigned u; } x; x.f = f;
  unsigned r = x.u + 0x7fffu + ((x.u >> 16) & 1u);
  return (u16)(r >> 16);
}

__device__ __forceinline__ f32x4 mfma16(u16x8 a, u16x8 b, f32x4 c) {
  return __builtin_amdgcn_mfma_f32_16x16x32_bf16(
      __builtin_bit_cast(b16x8_t, a), __builtin_bit_cast(b16x8_t, b), c, 0, 0, 0);
}

__device__ __forceinline__ void gld_lds16(const void* g, void* l) {
  __builtin_amdgcn_global_load_lds(
      (const __attribute__((address_space(1))) void*)g,
      (__attribute__((address_space(3))) void*)l, 16, 0, 0);
}

__device__ __forceinline__ void store_out(float* p, float v) { *p = v; }
__device__ __forceinline__ void store_out(u16* p, float v) { *p = f2bf(v); }

// ---------------- elementwise f32 -> bf16 ----------------
__global__ void convert_bf16(const float* __restrict__ src, u16* __restrict__ dst, int n4) {
  int i = blockIdx.x * blockDim.x + threadIdx.x;
  if (i < n4) {
    float4 f = ((const float4*)src)[i];
    u16 a0 = f2bf(f.x), a1 = f2bf(f.y), a2 = f2bf(f.z), a3 = f2bf(f.w);
    unsigned lo = (unsigned)a0 | ((unsigned)a1 << 16);
    unsigned hi = (unsigned)a2 | ((unsigned)a3 << 16);
    ((uint2*)dst)[i] = make_uint2(lo, hi);
  }
}

// ---------------- f32 [R][C] -> bf16 transposed [C][R] ----------------
__global__ void transpose_f32_bf16(const float* __restrict__ src, u16* __restrict__ dst,
                                   int R, int Cn) {
  __shared__ float t[32][33];
  int c0 = blockIdx.x * 32, r0 = blockIdx.y * 32;
  int tx = threadIdx.x, ty = threadIdx.y;  // (32,8)
  for (int j = 0; j < 32; j += 8)
    t[ty + j][tx] = src[(size_t)(r0 + ty + j) * Cn + c0 + tx];
  __syncthreads();
  for (int j = 0; j < 32; j += 8)
    dst[(size_t)(c0 + ty + j) * R + r0 + tx] = f2bf(t[tx][ty + j]);
}

// ---------------- V pre-transpose: qkv V-part -> Vt[(b*16+h)*64+k][n] ----------------
__global__ void transpose_v(const u16* __restrict__ QKV, u16* __restrict__ Vt) {
  __shared__ u16 t[64][72];
  const int tid = threadIdx.x;
  const int ntb = blockIdx.x, h = blockIdx.y, bb = blockIdx.z;
  const size_t rowb = (size_t)bb * 1024 + ntb * 64;
  const int colV = h * 192 + 128;
  for (int it = 0; it < 2; ++it) {
    int i2 = tid + it * 256;
    int n = i2 >> 3, kk = (i2 & 7) * 8;
    u16x8 v = *(const u16x8*)(QKV + (rowb + n) * 3072 + colV + kk);
#pragma unroll
    for (int u = 0; u < 8; ++u) t[kk + u][n] = v[u];
  }
  __syncthreads();
  const size_t vb = ((size_t)bb * 16 + h) * 64;
  for (int it = 0; it < 2; ++it) {
    int i2 = tid + it * 256;
    int k = i2 >> 3, ns = (i2 & 7) * 8;
    *(u16x8*)(Vt + (vb + k) * 1024 + ntb * 64 + ns) = *(const u16x8*)(&t[k][ns]);
  }
}

// ---------------- bf16 GEMM v3: C[M][N] = A[M][K] * Bt[N][K]^T ----------------
// BM=BN=128, BK=32, 4 LDS buffers (64 KiB -> 2 blocks/CU), 256 thr (4 waves 2x2),
// per-wave 64x64 (acc[4][4]). Phase = K-tile: 8 ds_read_b128 + stage(kt+3, 4 gld)
// + counted vmcnt(8) (drains exactly tile kt+1; never 0 mid-loop) + 2 barriers.
// Swizzle: 16B-chunk ^= (row>>1)&3 -> max 2-way bank aliasing (free, m136).
// T1 bijective XCD swizzle; T5 setprio (2 blocks/CU give it role diversity).
template <typename OutT, bool SCALEQ>
__global__ __launch_bounds__(256, 2) void gemm4p(const u16* __restrict__ A,
                                                 const u16* __restrict__ Bt,
                                                 OutT* __restrict__ C,
                                                 int M, int N, int K) {
  __shared__ __align__(16) u16 sA[4][4096];
  __shared__ __align__(16) u16 sB[4][4096];
  const int tid = threadIdx.x, lane = tid & 63, wid = tid >> 6;
  const int hi = lane >> 4, ln = lane & 15;
  const int wm = (wid >> 1) * 64, wn = (wid & 1) * 64;

  // XCD-aware bijective swizzle (nwg % 8 == 0 for both call sites)
  const int gdx = gridDim.x;
  const int nwg = gdx * gridDim.y;
  int wg = blockIdx.y * gdx + blockIdx.x;
  wg = (wg & 7) * (nwg >> 3) + (wg >> 3);
  const int m0 = (wg / gdx) * 128;
  const int n0 = (wg % gdx) * 128;

  // staging: thread -> row tid>>2 (and +64), 16B-chunk tid&3, source pre-swizzled
  const int sr = tid >> 2;
  const int scsw = ((tid & 3) ^ ((tid >> 3) & 3)) * 8;
  const u16* srcA0 = A + (size_t)(m0 + sr) * K + scsw;
  const u16* srcA1 = srcA0 + (size_t)64 * K;
  const u16* srcB0 = Bt + (size_t)(n0 + sr) * K + scsw;
  const u16* srcB1 = srcB0 + (size_t)64 * K;

  auto stage = [&](int t) {
    const int buf = t & 3;
    const int k0 = t * 32;
    gld_lds16(srcA0 + k0, &sA[buf][tid * 8]);
    gld_lds16(srcA1 + k0, &sA[buf][2048 + tid * 8]);
    gld_lds16(srcB0 + k0, &sB[buf][tid * 8]);
    gld_lds16(srcB1 + k0, &sB[buf][2048 + tid * 8]);
  };

  // fragment read offsets (u16 units): row*32 + (hi ^ ((ln>>1)&3))*8
  const int csw = (hi ^ ((ln >> 1) & 3)) * 8;
  int offA[4], offB[4];
#pragma unroll
  for (int i = 0; i < 4; ++i) offA[i] = (wm + i * 16 + ln) * 32 + csw;
#pragma unroll
  for (int j = 0; j < 4; ++j) offB[j] = (wn + j * 16 + ln) * 32 + csw;

  f32x4 acc[4][4] = {};
  const int NT = K >> 5;  // 32

  stage(0); stage(1); stage(2);
  asm volatile("s_waitcnt vmcnt(8)" ::: "memory");
  __builtin_amdgcn_s_barrier();

  for (int kt = 0; kt < NT; ++kt) {
    const int buf = kt & 3;
    u16x8 af[4], bf[4];
#pragma unroll
    for (int i = 0; i < 4; ++i) af[i] = *(const u16x8*)(&sA[buf][offA[i]]);
#pragma unroll
    for (int j = 0; j < 4; ++j) bf[j] = *(const u16x8*)(&sB[buf][offB[j]]);
    if (kt + 3 < NT) {
      stage(kt + 3);
      asm volatile("s_waitcnt vmcnt(8)" ::: "memory");   // tile kt+1 landed
    } else if (kt + 2 < NT) {
      asm volatile("s_waitcnt vmcnt(4)" ::: "memory");
    } else {
      asm volatile("s_waitcnt vmcnt(0)" ::: "memory");
    }
    __builtin_amdgcn_s_barrier();                         // kt+1 visible to all
    asm volatile("s_waitcnt lgkmcnt(0)" ::: "memory");    // frags in regs
    __builtin_amdgcn_sched_barrier(0);                    // rule 18
    __builtin_amdgcn_s_setprio(1);
#pragma unroll
    for (int i = 0; i < 4; ++i)
#pragma unroll
      for (int j = 0; j < 4; ++j)
        acc[i][j] = mfma16(af[i], bf[j], acc[i][j]);
    __builtin_amdgcn_s_setprio(0);
    __builtin_amdgcn_sched_barrier(0);
    __builtin_amdgcn_s_barrier();   // all waves' reads of buf done -> reuse safe
  }

  // epilogue: C/D layout col = lane&15, row = (lane>>4)*4 + reg
#pragma unroll
  for (int i = 0; i < 4; ++i) {
    int row = m0 + wm + i * 16 + hi * 4;
#pragma unroll
    for (int j = 0; j < 4; ++j) {
      int col = n0 + wn + j * 16 + ln;
      float sc = 1.f;
      if (SCALEQ) { if ((col % 192) < 64) sc = 0.125f; }
#pragma unroll
      for (int r = 0; r < 4; ++r)
        store_out(&C[(size_t)(row + r) * N + col], acc[i][j][r] * sc);
    }
  }
}

// ---------------- causal flash attention v2 ----------------
__global__ __launch_bounds__(512, 4) void attn_fwd2(const u16* __restrict__ QKV,
                                                    const u16* __restrict__ Vt,
                                                    u16* __restrict__ O) {
  __shared__ __align__(16) u16 sK[2][4096];
  __shared__ __align__(16) u16 sVt[2][4096];
  __shared__ __align__(16) u16 sP[8][16 * 72];
  const int tid = threadIdx.x, lane = tid & 63, wid = tid >> 6;
  const int z = blockIdx.x, h = blockIdx.y, bb = blockIdx.z;
  const size_t rowbase = (size_t)bb * 1024;
  const size_t vbase = ((size_t)bb * 16 + h) * 64;
  const int colQ = h * 192, colK = colQ + 64;
  const int hi = lane >> 4, ln = lane & 15;
  const int slr = lane >> 3;
  const int sle = ((lane & 7) ^ slr) * 8;
  u16* sPw = sP[wid];

  auto stageKV = [&](int buf, int nt) {
    const int n0g = nt * 64;
    gld_lds16(QKV + (rowbase + n0g + 8 * wid + slr) * 3072 + colK + sle,
              &sK[buf][wid * 512]);
    gld_lds16(Vt + (vbase + 8 * wid + slr) * 1024 + n0g + sle,
              &sVt[buf][wid * 512]);
  };

  for (int half = 0; half < 2; ++half) {
    const int mt = half ? (7 - z) : z;
    const int qrow0 = mt * 128 + wid * 16;
    const int ntiles = 2 * mt + 2;

    u16x8 qf[2];
#pragma unroll
    for (int kb = 0; kb < 2; ++kb)
      qf[kb] = *(const u16x8*)(QKV + (rowbase + qrow0 + ln) * 3072 + colQ + kb * 32 + hi * 8);

    f32x4 o[4] = {};
    float mrow[4], lrow[4];
#pragma unroll
    for (int r = 0; r < 4; ++r) { mrow[r] = -1e30f; lrow[r] = 0.f; }

    stageKV(0, 0);
    for (int nt = 0; nt < ntiles; ++nt) {
      __syncthreads();
      if (nt + 1 < ntiles) stageKV((nt + 1) & 1, nt + 1);
      const int buf = nt & 1;
      const int n0g = nt * 64;
      if (n0g <= qrow0 + 15) {
        f32x4 s[4] = {};
#pragma unroll
        for (int kb = 0; kb < 2; ++kb)
#pragma unroll
          for (int j = 0; j < 4; ++j) {
            int row = j * 16 + ln;
            int cb = (kb * 64 + hi * 16) ^ ((row & 7) << 4);
            u16x8 kfr = *(const u16x8*)(&sK[buf][(row * 128 + cb) >> 1]);
            s[j] = mfma16(qf[kb], kfr, s[j]);
          }
        if (n0g + 63 > qrow0) {
#pragma unroll
          for (int j = 0; j < 4; ++j) {
            int col = n0g + j * 16 + ln;
#pragma unroll
            for (int r = 0; r < 4; ++r)
              if (col > qrow0 + hi * 4 + r) s[j][r] = -3e38f;
          }
        }
#pragma unroll
        for (int r = 0; r < 4; ++r) {
          float tm = fmaxf(fmaxf(s[0][r], s[1][r]), fmaxf(s[2][r], s[3][r]));
#pragma unroll
          for (int d = 1; d < 16; d <<= 1) tm = fmaxf(tm, __shfl_xor(tm, d, 64));
          float mnew = fmaxf(mrow[r], tm);
          float corr = __expf(mrow[r] - mnew);
          mrow[r] = mnew;
          float rs = 0.f;
#pragma unroll
          for (int j = 0; j < 4; ++j) {
            float p = __expf(s[j][r] - mnew);
            s[j][r] = p;
            rs += p;
          }
#pragma unroll
          for (int d = 1; d < 16; d <<= 1) rs += __shfl_xor(rs, d, 64);
          lrow[r] = lrow[r] * corr + rs;
#pragma unroll
          for (int dt = 0; dt < 4; ++dt) o[dt][r] *= corr;
        }
#pragma unroll
        for (int j = 0; j < 4; ++j)
#pragma unroll
          for (int r = 0; r < 4; ++r)
            sPw[(hi * 4 + r) * 72 + j * 16 + ln] = f2bf(s[j][r]);
        u16x8 pf[2];
#pragma unroll
        for (int kb2 = 0; kb2 < 2; ++kb2)
          pf[kb2] = *(const u16x8*)(&sPw[ln * 72 + kb2 * 32 + hi * 8]);
#pragma unroll
        for (int dt = 0; dt < 4; ++dt)
#pragma unroll
          for (int kb2 = 0; kb2 < 2; ++kb2) {
            int row = dt * 16 + ln;
            int cb = (kb2 * 64 + hi * 16) ^ ((row & 7) << 4);
            u16x8 vfr = *(const u16x8*)(&sVt[buf][(row * 128 + cb) >> 1]);
            o[dt] = mfma16(pf[kb2], vfr, o[dt]);
          }
      }
    }
#pragma unroll
    for (int r = 0; r < 4; ++r) {
      float inv = 1.f / lrow[r];
#pragma unroll
      for (int dt = 0; dt < 4; ++dt)
        O[(rowbase + qrow0 + hi * 4 + r) * 1024 + h * 64 + dt * 16 + ln] =
            f2bf(o[dt][r] * inv);
    }
  }
}

extern "C" void kernel_launch(void* const* d_in, const int* in_sizes, int n_in,
                              void* d_out, int out_size, void* d_ws, size_t ws_size,
                              hipStream_t stream) {
  const float* x = (const float*)d_in[0];
  const float* Pi = (const float*)d_in[1];
  const float* Po = (const float*)d_in[2];
  float* y = (float*)d_out;
  char* ws = (char*)d_ws;

  u16* qkv  = (u16*)(ws);                     // 50331648
  u16* xbf  = (u16*)(ws + 50331648);          // 16777216
  u16* vt   = (u16*)(ws + 50331648);          // reuses xbf slot
  u16* piT  = (u16*)(ws + 67108864);          // 6291456
  u16* poT  = (u16*)(ws + 73400320);          // 2097152
  u16* obuf = (u16*)(ws + 75497472);          // 16777216

  convert_bf16<<<8192, 256, 0, stream>>>(x, xbf, 8388608 / 4);
  dim3 tb(32, 8);
  transpose_f32_bf16<<<dim3(96, 32), tb, 0, stream>>>(Pi, piT, 1024, 3072);
  transpose_f32_bf16<<<dim3(32, 32), tb, 0, stream>>>(Po, poT, 1024, 1024);

  gemm4p<u16, true><<<dim3(24, 64), 256, 0, stream>>>(xbf, piT, qkv, 8192, 3072, 1024);
  transpose_v<<<dim3(16, 16, 8), 256, 0, stream>>>(qkv, vt);
  attn_fwd2<<<dim3(4, 16, 8), 512, 0, stream>>>(qkv, vt, obuf);
  gemm4p<float, false><<<dim3(8, 64), 256, 0, stream>>>(obuf, poT, y, 8192, 1024, 1024);
}

// Round 6
// 173.353 us; speedup vs baseline: 1.1619x; 1.0408x over previous
//
#include <hip/hip_runtime.h>

typedef unsigned short u16;
typedef __bf16 b16x8_t __attribute__((ext_vector_type(8)));
typedef unsigned short u16x8 __attribute__((ext_vector_type(8)));
typedef float f32x4 __attribute__((ext_vector_type(4)));

__device__ __forceinline__ u16 f2bf(float f) {
  union { float f; unsigned u; } x; x.f = f;
  unsigned r = x.u + 0x7fffu + ((x.u >> 16) & 1u);
  return (u16)(r >> 16);
}

__device__ __forceinline__ f32x4 mfma16(u16x8 a, u16x8 b, f32x4 c) {
  return __builtin_amdgcn_mfma_f32_16x16x32_bf16(
      __builtin_bit_cast(b16x8_t, a), __builtin_bit_cast(b16x8_t, b), c, 0, 0, 0);
}

__device__ __forceinline__ void gld_lds16(const void* g, void* l) {
  __builtin_amdgcn_global_load_lds(
      (const __attribute__((address_space(1))) void*)g,
      (__attribute__((address_space(3))) void*)l, 16, 0, 0);
}

__device__ __forceinline__ void store_out(float* p, float v) { *p = v; }
__device__ __forceinline__ void store_out(u16* p, float v) { *p = f2bf(v); }

// ---------------- elementwise f32 -> bf16 ----------------
__global__ void convert_bf16(const float* __restrict__ src, u16* __restrict__ dst, int n4) {
  int i = blockIdx.x * blockDim.x + threadIdx.x;
  if (i < n4) {
    float4 f = ((const float4*)src)[i];
    u16 a0 = f2bf(f.x), a1 = f2bf(f.y), a2 = f2bf(f.z), a3 = f2bf(f.w);
    unsigned lo = (unsigned)a0 | ((unsigned)a1 << 16);
    unsigned hi = (unsigned)a2 | ((unsigned)a3 << 16);
    ((uint2*)dst)[i] = make_uint2(lo, hi);
  }
}

// ---------------- f32 [R][C] -> bf16 transposed [C][R] ----------------
__global__ void transpose_f32_bf16(const float* __restrict__ src, u16* __restrict__ dst,
                                   int R, int Cn) {
  __shared__ float t[32][33];
  int c0 = blockIdx.x * 32, r0 = blockIdx.y * 32;
  int tx = threadIdx.x, ty = threadIdx.y;  // (32,8)
  for (int j = 0; j < 32; j += 8)
    t[ty + j][tx] = src[(size_t)(r0 + ty + j) * Cn + c0 + tx];
  __syncthreads();
  for (int j = 0; j < 32; j += 8)
    dst[(size_t)(c0 + ty + j) * R + r0 + tx] = f2bf(t[tx][ty + j]);
}

// ---------------- V pre-transpose: qkv V-part -> Vt[(b*16+h)*64+k][n] ----------------
__global__ void transpose_v(const u16* __restrict__ QKV, u16* __restrict__ Vt) {
  __shared__ u16 t[64][72];
  const int tid = threadIdx.x;
  const int ntb = blockIdx.x, h = blockIdx.y, bb = blockIdx.z;
  const size_t rowb = (size_t)bb * 1024 + ntb * 64;
  const int colV = h * 192 + 128;
  for (int it = 0; it < 2; ++it) {
    int i2 = tid + it * 256;
    int n = i2 >> 3, kk = (i2 & 7) * 8;
    u16x8 v = *(const u16x8*)(QKV + (rowb + n) * 3072 + colV + kk);
#pragma unroll
    for (int u = 0; u < 8; ++u) t[kk + u][n] = v[u];
  }
  __syncthreads();
  const size_t vb = ((size_t)bb * 16 + h) * 64;
  for (int it = 0; it < 2; ++it) {
    int i2 = tid + it * 256;
    int k = i2 >> 3, ns = (i2 & 7) * 8;
    *(u16x8*)(Vt + (vb + k) * 1024 + ntb * 64 + ns) = *(const u16x8*)(&t[k][ns]);
  }
}

// ---------------- bf16 GEMM v4 (wave-tile 128x64): C = A * Bt^T ----------------
// BM=256, BN=128, BK=32, 4 waves (2Mx2N), per-wave 128x64 (acc[8][4]).
// Ratio = 128*64/(128+64) = 42.7 FLOP/LDS-byte (vs 32 for 64x64 tiles) -> lifts
// the LDS-fragment-BW ceiling that pinned MfmaUtil at ~28%.
// 3 LDS buffers (72 KiB -> 2 blocks/CU), counted vmcnt (stage kt+2; vmcnt(6)
// == tile kt+1 landed; never 0 mid-loop), 2 barriers/K-step, setprio on the
// 32-MFMA cluster. Zero-conflict swizzle: chunk ^= (row>>1)&3, row-block-invariant.
template <typename OutT, bool SCALEQ>
__global__ __launch_bounds__(256, 2) void gemm_wt(const u16* __restrict__ A,
                                                  const u16* __restrict__ Bt,
                                                  OutT* __restrict__ C,
                                                  int M, int N, int K) {
  __shared__ __align__(16) u16 sA[3][8192];   // 256 x 32
  __shared__ __align__(16) u16 sB[3][4096];   // 128 x 32
  const int tid = threadIdx.x, lane = tid & 63, wid = tid >> 6;
  const int hi = lane >> 4, ln = lane & 15;
  const int wm = (wid >> 1) * 128, wn = (wid & 1) * 64;

  // XCD-aware bijective swizzle (nwg % 8 == 0 for both call sites)
  const int gdx = gridDim.x;
  const int nwg = gdx * gridDim.y;
  int wg = blockIdx.y * gdx + blockIdx.x;
  wg = (wg & 7) * (nwg >> 3) + (wg >> 3);
  const int m0 = (wg / gdx) * 256;
  const int n0 = (wg % gdx) * 128;

  // staging: thread -> row tid>>2 (+64/128/192), 16B-chunk tid&3, src pre-swizzled
  const int sr = tid >> 2;
  const int scsw = ((tid & 3) ^ ((tid >> 3) & 3)) * 8;
  const u16* srcA = A + (size_t)(m0 + sr) * K + scsw;
  const u16* srcB = Bt + (size_t)(n0 + sr) * K + scsw;
  const size_t K64 = (size_t)64 * K;

  auto stage = [&](int buf, int t) {
    const int k0 = t * 32;
    gld_lds16(srcA + k0, &sA[buf][tid * 8]);
    gld_lds16(srcA + K64 + k0, &sA[buf][2048 + tid * 8]);
    gld_lds16(srcA + 2 * K64 + k0, &sA[buf][4096 + tid * 8]);
    gld_lds16(srcA + 3 * K64 + k0, &sA[buf][6144 + tid * 8]);
    gld_lds16(srcB + k0, &sB[buf][tid * 8]);
    gld_lds16(srcB + K64 + k0, &sB[buf][2048 + tid * 8]);
  };

  // fragment read offsets (u16 units): row*32 + (hi ^ ((ln>>1)&3))*8
  const int csw = (hi ^ ((ln >> 1) & 3)) * 8;
  int offA[8], offB[4];
#pragma unroll
  for (int i = 0; i < 8; ++i) offA[i] = (wm + i * 16 + ln) * 32 + csw;
#pragma unroll
  for (int j = 0; j < 4; ++j) offB[j] = (wn + j * 16 + ln) * 32 + csw;

  f32x4 acc[8][4] = {};
  const int NT = K >> 5;  // 32

  stage(0, 0); stage(1, 1);
  asm volatile("s_waitcnt vmcnt(6)" ::: "memory");   // tile 0 landed
  __builtin_amdgcn_s_barrier();

  int cb = 0, sb = 2;
  for (int kt = 0; kt < NT; ++kt) {
    u16x8 af[8], bf[4];
#pragma unroll
    for (int i = 0; i < 8; ++i) af[i] = *(const u16x8*)(&sA[cb][offA[i]]);
#pragma unroll
    for (int j = 0; j < 4; ++j) bf[j] = *(const u16x8*)(&sB[cb][offB[j]]);
    if (kt + 2 < NT) {
      stage(sb, kt + 2);
      sb = (sb == 2) ? 0 : sb + 1;
      asm volatile("s_waitcnt vmcnt(6)" ::: "memory");  // tile kt+1 landed
    } else {
      asm volatile("s_waitcnt vmcnt(0)" ::: "memory");
    }
    __builtin_amdgcn_s_barrier();                       // kt+1 visible to all
    asm volatile("s_waitcnt lgkmcnt(0)" ::: "memory");  // frags in regs
    __builtin_amdgcn_sched_barrier(0);                  // rule 18
    __builtin_amdgcn_s_setprio(1);
#pragma unroll
    for (int i = 0; i < 8; ++i)
#pragma unroll
      for (int j = 0; j < 4; ++j)
        acc[i][j] = mfma16(af[i], bf[j], acc[i][j]);
    __builtin_amdgcn_s_setprio(0);
    __builtin_amdgcn_sched_barrier(0);
    __builtin_amdgcn_s_barrier();   // all reads of cb done -> overwrite safe
    cb = (cb == 2) ? 0 : cb + 1;
  }

  // epilogue: C/D layout col = lane&15, row = (lane>>4)*4 + reg
#pragma unroll
  for (int i = 0; i < 8; ++i) {
    int row = m0 + wm + i * 16 + hi * 4;
#pragma unroll
    for (int j = 0; j < 4; ++j) {
      int col = n0 + wn + j * 16 + ln;
      float sc = 1.f;
      if (SCALEQ) { if ((col % 192) < 64) sc = 0.125f; }
#pragma unroll
      for (int r = 0; r < 4; ++r)
        store_out(&C[(size_t)(row + r) * N + col], acc[i][j][r] * sc);
    }
  }
}

// ---------------- causal flash attention v2 ----------------
__global__ __launch_bounds__(512, 4) void attn_fwd2(const u16* __restrict__ QKV,
                                                    const u16* __restrict__ Vt,
                                                    u16* __restrict__ O) {
  __shared__ __align__(16) u16 sK[2][4096];
  __shared__ __align__(16) u16 sVt[2][4096];
  __shared__ __align__(16) u16 sP[8][16 * 72];
  const int tid = threadIdx.x, lane = tid & 63, wid = tid >> 6;
  const int z = blockIdx.x, h = blockIdx.y, bb = blockIdx.z;
  const size_t rowbase = (size_t)bb * 1024;
  const size_t vbase = ((size_t)bb * 16 + h) * 64;
  const int colQ = h * 192, colK = colQ + 64;
  const int hi = lane >> 4, ln = lane & 15;
  const int slr = lane >> 3;
  const int sle = ((lane & 7) ^ slr) * 8;
  u16* sPw = sP[wid];

  auto stageKV = [&](int buf, int nt) {
    const int n0g = nt * 64;
    gld_lds16(QKV + (rowbase + n0g + 8 * wid + slr) * 3072 + colK + sle,
              &sK[buf][wid * 512]);
    gld_lds16(Vt + (vbase + 8 * wid + slr) * 1024 + n0g + sle,
              &sVt[buf][wid * 512]);
  };

  for (int half = 0; half < 2; ++half) {
    const int mt = half ? (7 - z) : z;
    const int qrow0 = mt * 128 + wid * 16;
    const int ntiles = 2 * mt + 2;

    u16x8 qf[2];
#pragma unroll
    for (int kb = 0; kb < 2; ++kb)
      qf[kb] = *(const u16x8*)(QKV + (rowbase + qrow0 + ln) * 3072 + colQ + kb * 32 + hi * 8);

    f32x4 o[4] = {};
    float mrow[4], lrow[4];
#pragma unroll
    for (int r = 0; r < 4; ++r) { mrow[r] = -1e30f; lrow[r] = 0.f; }

    stageKV(0, 0);
    for (int nt = 0; nt < ntiles; ++nt) {
      __syncthreads();
      if (nt + 1 < ntiles) stageKV((nt + 1) & 1, nt + 1);
      const int buf = nt & 1;
      const int n0g = nt * 64;
      if (n0g <= qrow0 + 15) {
        f32x4 s[4] = {};
#pragma unroll
        for (int kb = 0; kb < 2; ++kb)
#pragma unroll
          for (int j = 0; j < 4; ++j) {
            int row = j * 16 + ln;
            int cb = (kb * 64 + hi * 16) ^ ((row & 7) << 4);
            u16x8 kfr = *(const u16x8*)(&sK[buf][(row * 128 + cb) >> 1]);
            s[j] = mfma16(qf[kb], kfr, s[j]);
          }
        if (n0g + 63 > qrow0) {
#pragma unroll
          for (int j = 0; j < 4; ++j) {
            int col = n0g + j * 16 + ln;
#pragma unroll
            for (int r = 0; r < 4; ++r)
              if (col > qrow0 + hi * 4 + r) s[j][r] = -3e38f;
          }
        }
#pragma unroll
        for (int r = 0; r < 4; ++r) {
          float tm = fmaxf(fmaxf(s[0][r], s[1][r]), fmaxf(s[2][r], s[3][r]));
#pragma unroll
          for (int d = 1; d < 16; d <<= 1) tm = fmaxf(tm, __shfl_xor(tm, d, 64));
          float mnew = fmaxf(mrow[r], tm);
          float corr = __expf(mrow[r] - mnew);
          mrow[r] = mnew;
          float rs = 0.f;
#pragma unroll
          for (int j = 0; j < 4; ++j) {
            float p = __expf(s[j][r] - mnew);
            s[j][r] = p;
            rs += p;
          }
#pragma unroll
          for (int d = 1; d < 16; d <<= 1) rs += __shfl_xor(rs, d, 64);
          lrow[r] = lrow[r] * corr + rs;
#pragma unroll
          for (int dt = 0; dt < 4; ++dt) o[dt][r] *= corr;
        }
#pragma unroll
        for (int j = 0; j < 4; ++j)
#pragma unroll
          for (int r = 0; r < 4; ++r)
            sPw[(hi * 4 + r) * 72 + j * 16 + ln] = f2bf(s[j][r]);
        u16x8 pf[2];
#pragma unroll
        for (int kb2 = 0; kb2 < 2; ++kb2)
          pf[kb2] = *(const u16x8*)(&sPw[ln * 72 + kb2 * 32 + hi * 8]);
#pragma unroll
        for (int dt = 0; dt < 4; ++dt)
#pragma unroll
          for (int kb2 = 0; kb2 < 2; ++kb2) {
            int row = dt * 16 + ln;
            int cb = (kb2 * 64 + hi * 16) ^ ((row & 7) << 4);
            u16x8 vfr = *(const u16x8*)(&sVt[buf][(row * 128 + cb) >> 1]);
            o[dt] = mfma16(pf[kb2], vfr, o[dt]);
          }
      }
    }
#pragma unroll
    for (int r = 0; r < 4; ++r) {
      float inv = 1.f / lrow[r];
#pragma unroll
      for (int dt = 0; dt < 4; ++dt)
        O[(rowbase + qrow0 + hi * 4 + r) * 1024 + h * 64 + dt * 16 + ln] =
            f2bf(o[dt][r] * inv);
    }
  }
}

extern "C" void kernel_launch(void* const* d_in, const int* in_sizes, int n_in,
                              void* d_out, int out_size, void* d_ws, size_t ws_size,
                              hipStream_t stream) {
  const float* x = (const float*)d_in[0];
  const float* Pi = (const float*)d_in[1];
  const float* Po = (const float*)d_in[2];
  float* y = (float*)d_out;
  char* ws = (char*)d_ws;

  u16* qkv  = (u16*)(ws);                     // 50331648
  u16* xbf  = (u16*)(ws + 50331648);          // 16777216
  u16* vt   = (u16*)(ws + 50331648);          // reuses xbf slot
  u16* piT  = (u16*)(ws + 67108864);          // 6291456
  u16* poT  = (u16*)(ws + 73400320);          // 2097152
  u16* obuf = (u16*)(ws + 75497472);          // 16777216

  convert_bf16<<<8192, 256, 0, stream>>>(x, xbf, 8388608 / 4);
  dim3 tb(32, 8);
  transpose_f32_bf16<<<dim3(96, 32), tb, 0, stream>>>(Pi, piT, 1024, 3072);
  transpose_f32_bf16<<<dim3(32, 32), tb, 0, stream>>>(Po, poT, 1024, 1024);

  gemm_wt<u16, true><<<dim3(24, 32), 256, 0, stream>>>(xbf, piT, qkv, 8192, 3072, 1024);
  transpose_v<<<dim3(16, 16, 8), 256, 0, stream>>>(qkv, vt);
  attn_fwd2<<<dim3(4, 16, 8), 512, 0, stream>>>(qkv, vt, obuf);
  gemm_wt<float, false><<<dim3(8, 32), 256, 0, stream>>>(obuf, poT, y, 8192, 1024, 1024);
}